// Round 5
// baseline (228.474 us; speedup 1.0000x reference)
//
#include <hip/hip_runtime.h>
#include <cstddef>

#define B   4
#define D   512
#define T   2048
#define H   8
#define DH  64
#define NEG_SLOPE 0.2f
#define EPS 1e-6f
#define LOG2E 1.44269504088896340736f

typedef __attribute__((ext_vector_type(8))) short short8;   // 8 x bf16 (4 VGPRs)
typedef __attribute__((ext_vector_type(4))) float float4v;  // 4 x f32

__device__ __forceinline__ float bf2f(ushort u) {
    unsigned int x = ((unsigned int)u) << 16;
    return __builtin_bit_cast(float, x);
}
__device__ __forceinline__ ushort f2bf(float f) {
    unsigned int x = __builtin_bit_cast(unsigned int, f);
    x = x + 0x7fffu + ((x >> 16) & 1u);   // round-to-nearest-even
    return (ushort)(x >> 16);
}

// -----------------------------------------------------------------------------
// Kernel A: 64x64-tiled transpose fp32 -> bf16, optional leaky-ReLU.
// Block (0,0,0) also zeroes zbuf (ssq accumulator) when zbuf != nullptr.
// -----------------------------------------------------------------------------
__global__ __launch_bounds__(256) void transpose_lrelu(const float* __restrict__ src,
                                                       ushort* __restrict__ dst,
                                                       int src_ld, int dst_ld,
                                                       size_t src_mstride, size_t dst_mstride,
                                                       int do_lrelu,
                                                       float* __restrict__ zbuf, int zcount) {
    const int tid = threadIdx.x;
    if (zbuf != nullptr && blockIdx.x == 0 && blockIdx.y == 0 && blockIdx.z == 0) {
        for (int i = tid; i < zcount; i += 256) zbuf[i] = 0.f;
    }

    const int c0 = blockIdx.x * 64, r0 = blockIdx.y * 64;
    const float* s = src + blockIdx.z * src_mstride + (size_t)r0 * src_ld + c0;
    ushort*      d = dst + blockIdx.z * dst_mstride + (size_t)c0 * dst_ld + r0;

    __shared__ float Ls[64][68];

    const int rl = tid >> 4, c4 = (tid & 15) * 4;
    #pragma unroll
    for (int p = 0; p < 4; ++p) {
        float4 v = *(const float4*)(s + (size_t)(rl + p * 16) * src_ld + c4);
        if (do_lrelu) {
            v.x = fmaxf(v.x, NEG_SLOPE * v.x);
            v.y = fmaxf(v.y, NEG_SLOPE * v.y);
            v.z = fmaxf(v.z, NEG_SLOPE * v.z);
            v.w = fmaxf(v.w, NEG_SLOPE * v.w);
        }
        *(float4*)&Ls[rl + p * 16][c4] = v;
    }
    __syncthreads();

    const int tl = tid >> 2;
    #pragma unroll
    for (int it = 0; it < 2; ++it) {
        int ch = (tid & 3) + it * 4;
        ushort o[8];
        #pragma unroll
        for (int j = 0; j < 8; ++j) o[j] = f2bf(Ls[ch * 8 + j][tl]);
        *(uint4*)(d + (size_t)tl * dst_ld + ch * 8) = *(uint4*)o;
    }
}

// -----------------------------------------------------------------------------
// Kernel B: QKV GEMM via bf16 MFMA. C[b][t][gd] = sum_d xT[b][t][d] * WT[gd][d]
// Q/K heads -> hb[t][dh]; V heads -> vT[dd][t]. Accumulates per-channel sumsq.
// (Round-5: reverted to the round-0/3 version — the round-4 2-phase rewrite
// was neutral-to-negative; this one carries the best measured total.)
// -----------------------------------------------------------------------------
__global__ __launch_bounds__(256) void qkv_mm(const ushort* __restrict__ xT,
                                              const ushort* __restrict__ WT,
                                              ushort* __restrict__ hb,
                                              ushort* __restrict__ vT,
                                              float* __restrict__ ssq) {
    const int tid = threadIdx.x, wave = tid >> 6, lane = tid & 63;
    const int quad = lane >> 4, l16 = lane & 15;
    const int wr = wave >> 1, wc = wave & 1;
    const int t0  = blockIdx.x * 128;
    const int gd0 = blockIdx.y * 128;
    const int b   = blockIdx.z;

    __shared__ ushort At[128 * 64];
    __shared__ ushort Bt[128 * 64];

    const ushort* xb = xT + (size_t)b * T * D + (size_t)t0 * D;
    const ushort* wb = WT + (size_t)gd0 * D;

    const int srow = lane >> 3;
    const int csrc = (lane & 7) ^ srow;

    float4v acc[4][4];
    #pragma unroll
    for (int i = 0; i < 4; ++i)
        #pragma unroll
        for (int j = 0; j < 4; ++j) acc[i][j] = (float4v){0.f, 0.f, 0.f, 0.f};

    for (int k0 = 0; k0 < D; k0 += 64) {
        #pragma unroll
        for (int i = 0; i < 4; ++i) {
            int rbase = wave * 32 + i * 8;
            int row = rbase + srow;
            const ushort* ga = xb + (size_t)row * D + k0 + csrc * 8;
            const ushort* gb = wb + (size_t)row * D + k0 + csrc * 8;
            __builtin_amdgcn_global_load_lds(
                (const __attribute__((address_space(1))) unsigned int*)ga,
                (__attribute__((address_space(3))) unsigned int*)&At[rbase * 64], 16, 0, 0);
            __builtin_amdgcn_global_load_lds(
                (const __attribute__((address_space(1))) unsigned int*)gb,
                (__attribute__((address_space(3))) unsigned int*)&Bt[rbase * 64], 16, 0, 0);
        }
        __syncthreads();

        #pragma unroll
        for (int kh = 0; kh < 2; ++kh) {
            short8 aF[4], bF[4];
            #pragma unroll
            for (int mt = 0; mt < 4; ++mt) {
                int row = wr * 64 + mt * 16 + l16;
                aF[mt] = *(const short8*)&At[row * 64 + (((kh * 4 + quad) ^ (l16 & 7)) * 8)];
            }
            #pragma unroll
            for (int nt = 0; nt < 4; ++nt) {
                int row = wc * 64 + nt * 16 + l16;
                bF[nt] = *(const short8*)&Bt[row * 64 + (((kh * 4 + quad) ^ (l16 & 7)) * 8)];
            }
            #pragma unroll
            for (int mt = 0; mt < 4; ++mt)
                #pragma unroll
                for (int nt = 0; nt < 4; ++nt)
                    acc[mt][nt] = __builtin_amdgcn_mfma_f32_16x16x32_bf16(
                        aF[mt], bF[nt], acc[mt][nt], 0, 0, 0);
        }
        __syncthreads();
    }

    const int g = blockIdx.y * 2 + wc;       // 0..23
    const int n = g >> 3, hh = g & 7;
    float colsq[4] = {0.f, 0.f, 0.f, 0.f};

    if (n < 2) {
        ushort* hbase = hb + (((size_t)n * B + b) * H + hh) * (size_t)T * DH;
        #pragma unroll
        for (int mt = 0; mt < 4; ++mt) {
            #pragma unroll
            for (int nt = 0; nt < 4; ++nt) {
                float4v c = acc[mt][nt];
                int dd = nt * 16 + l16;
                #pragma unroll
                for (int r = 0; r < 4; ++r) {
                    int t = t0 + wr * 64 + mt * 16 + quad * 4 + r;
                    hbase[(size_t)t * DH + dd] = f2bf(c[r]);
                    colsq[nt] += c[r] * c[r];
                }
            }
        }
    } else {
        ushort* vbase = vT + ((size_t)b * H + hh) * (size_t)DH * T;
        #pragma unroll
        for (int mt = 0; mt < 4; ++mt) {
            #pragma unroll
            for (int nt = 0; nt < 4; ++nt) {
                float4v c = acc[mt][nt];
                int dd = nt * 16 + l16;
                int t  = t0 + wr * 64 + mt * 16 + quad * 4;
                ushort4 pk;
                pk.x = f2bf(c[0]); pk.y = f2bf(c[1]);
                pk.z = f2bf(c[2]); pk.w = f2bf(c[3]);
                *(ushort4*)(vbase + (size_t)dd * T + t) = pk;
                colsq[nt] += c[0]*c[0] + c[1]*c[1] + c[2]*c[2] + c[3]*c[3];
            }
        }
    }
    #pragma unroll
    for (int nt = 0; nt < 4; ++nt) {
        float s = colsq[nt];
        s += __shfl_xor(s, 16);
        s += __shfl_xor(s, 32);
        if (quad == 0)
            atomicAdd(&ssq[(((size_t)n * B + b) * H + hh) * 64 + nt * 16 + l16], s);
    }
}

// -----------------------------------------------------------------------------
// Kernel C: flash attention, S^T = K*Q^T, NO online max (scores ~N(0,1):
// exp2 cannot overflow fp32/bf16 exponent range). log2e folded into Q scale.
//
// Round-5: round-3 structure (16 q/wave, grid 1024 = 16 waves/CU, K dbuf in
// LDS) with ONE lever: V fragments read DIRECTLY from global in PV (verbatim
// round-2 load, which passed correctness). Rationale: per-CU LDS-pipe model
// (18 b128 reads + 4 b64 writes = ~240cyc per wave-tile -> 123Kcyc/CU = 51us)
// matches the measured 59us across 3 rounds; V (256KB/head) is L2-resident per
// XCD (catalog m169: don't stage what cache-fits). Moving V's 8 reads/tile to
// the idle L1/VMEM pipe cuts LDS to ~74Kcyc/CU; intra-block 4-wave V reuse is
// L1-resident. Vt deleted; 2 barriers/tile -> 1 (PV needs no barrier: Pb is
// wave-private, aV comes from registers).
// -----------------------------------------------------------------------------
__global__ __launch_bounds__(256, 4) void flash_attn(const ushort* __restrict__ hb,
                                                     const ushort* __restrict__ vT,
                                                     const float* __restrict__ ssq,
                                                     const float* __restrict__ norm_w,
                                                     float* __restrict__ out) {
    const int tid  = threadIdx.x;
    const int wave = tid >> 6;
    const int lane = tid & 63;
    const int quad = lane >> 4;
    const int l16  = lane & 15;

    // XCD-locality remap: all 32 t-tiles of a head land on one XCD
    const int lin  = blockIdx.x;
    const int head = ((lin & 7) << 2) | ((lin >> 3) & 3);   // b*H+hh
    const int t0   = (lin >> 5) * 64;
    const int b    = head >> 3, hh = head & 7;

    const size_t slab = (size_t)B * H * T * DH;
    const ushort* qp = hb + (size_t)head * T * DH;
    const ushort* kp = hb + slab + (size_t)head * T * DH;
    const ushort* vp = vT + (size_t)head * DH * T;

    __shared__ ushort Kt[2][64 * 64];     // 16 KB, double-buffered K tile
    __shared__ ushort Pb[4][16 * 64];     // 8 KB, wave-private quadrants
    __shared__ float fqk[64], sv[64];

    if (tid < 64) {
        float nw = norm_w[0];
        float mq = ssq[(0 * B * H + head) * 64 + tid] * (1.0f / T) + EPS;
        float mk = ssq[(1 * B * H + head) * 64 + tid] * (1.0f / T) + EPS;
        float mv = ssq[(2 * B * H + head) * 64 + tid] * (1.0f / T) + EPS;
        fqk[tid] = nw * nw * rsqrtf(mq) * rsqrtf(mk) * 0.125f * LOG2E;
        sv[tid]  = nw * rsqrtf(mv);
    }

    // ---- staging lane constants (pre-swizzled global source, linear LDS)
    const int srow = lane >> 3;
    const int csrc = (lane & 7) ^ srow;
    const ushort* kA = kp + (size_t)(wave * 16 + srow) * DH + csrc * 8;
    const ushort* kB = kp + (size_t)(wave * 16 + 8 + srow) * DH + csrc * 8;

    // ---- prologue: stage K tile 0 into buffer 0 (drained by the barrier below)
    __builtin_amdgcn_global_load_lds(
        (const __attribute__((address_space(1))) unsigned int*)kA,
        (__attribute__((address_space(3))) unsigned int*)&Kt[0][(wave * 16) * 64], 16, 0, 0);
    __builtin_amdgcn_global_load_lds(
        (const __attribute__((address_space(1))) unsigned int*)kB,
        (__attribute__((address_space(3))) unsigned int*)&Kt[0][(wave * 16 + 8) * 64], 16, 0, 0);

    // ---- Q B-frags (col = query = l16), pre-scaled by fqk (incl. log2e)
    __syncthreads();          // fqk/sv ready + K(0) staged & visible
    short8 bQ[2];
    {
        const ushort* qr = qp + (size_t)(t0 + wave * 16 + l16) * DH;
        #pragma unroll
        for (int kh = 0; kh < 2; ++kh) {
            short8 raw = *(const short8*)(qr + kh * 32 + quad * 8);
            #pragma unroll
            for (int j = 0; j < 8; ++j) {
                float f = bf2f((ushort)raw[j]) * fqk[kh * 32 + quad * 8 + j];
                bQ[kh][j] = (short)f2bf(f);
            }
        }
    }

    float l_run = 0.f;
    float4v O[4];
    #pragma unroll
    for (int dt = 0; dt < 4; ++dt) O[dt] = (float4v){0.f, 0.f, 0.f, 0.f};

    int cur = 0;
    for (int j0 = 0; j0 < T; j0 += 64) {
        // ---- issue K(j+1) prefetch into the other buffer
        if (j0 + 64 < T) {
            __builtin_amdgcn_global_load_lds(
                (const __attribute__((address_space(1))) unsigned int*)(kA + (size_t)(j0 + 64) * DH),
                (__attribute__((address_space(3))) unsigned int*)&Kt[cur ^ 1][(wave * 16) * 64], 16, 0, 0);
            __builtin_amdgcn_global_load_lds(
                (const __attribute__((address_space(1))) unsigned int*)(kB + (size_t)(j0 + 64) * DH),
                (__attribute__((address_space(3))) unsigned int*)&Kt[cur ^ 1][(wave * 16 + 8) * 64], 16, 0, 0);
        }

        // ---- V fragments for THIS tile: direct 16B/lane global loads
        // (round-2-verified pattern; L1/L2-resident; consumed in PV below,
        // waitcnt'd by the compiler right before use)
        short8 aV[2][4];
        #pragma unroll
        for (int kh = 0; kh < 2; ++kh)
            #pragma unroll
            for (int dt = 0; dt < 4; ++dt)
                aV[kh][dt] = *(const short8*)(vp + (size_t)(dt * 16 + l16) * T
                                              + j0 + kh * 32 + quad * 8);

        // ---- S^T = K * Q^T from Kt[cur] (staged last iter, already visible)
        float4v S[4];
        #pragma unroll
        for (int mt = 0; mt < 4; ++mt) S[mt] = (float4v){0.f, 0.f, 0.f, 0.f};
        #pragma unroll
        for (int kh = 0; kh < 2; ++kh) {
            #pragma unroll
            for (int mt = 0; mt < 4; ++mt) {
                int row = mt * 16 + l16;
                short8 aK = *(const short8*)&Kt[cur][row * 64 + (((kh * 4 + quad) ^ (l16 & 7)) * 8)];
                S[mt] = __builtin_amdgcn_mfma_f32_16x16x32_bf16(aK, bQ[kh], S[mt], 0, 0, 0);
            }
        }

        // ---- P = exp2(S), accumulate partial l, pack to bf16 via v_perm
        #pragma unroll
        for (int mt = 0; mt < 4; ++mt) {
            float p0 = __builtin_amdgcn_exp2f(S[mt][0]);
            float p1 = __builtin_amdgcn_exp2f(S[mt][1]);
            float p2 = __builtin_amdgcn_exp2f(S[mt][2]);
            float p3 = __builtin_amdgcn_exp2f(S[mt][3]);
            l_run += (p0 + p1) + (p2 + p3);
            unsigned int a0 = __builtin_bit_cast(unsigned int, p0) + 0x8000u;
            unsigned int a1 = __builtin_bit_cast(unsigned int, p1) + 0x8000u;
            unsigned int a2 = __builtin_bit_cast(unsigned int, p2) + 0x8000u;
            unsigned int a3 = __builtin_bit_cast(unsigned int, p3) + 0x8000u;
            uint2 pk;
            pk.x = __builtin_amdgcn_perm(a1, a0, 0x07060302u);
            pk.y = __builtin_amdgcn_perm(a3, a2, 0x07060302u);
            *(uint2*)&Pb[wave][l16 * 64 + (((mt * 2 + (quad >> 1)) ^ (l16 & 7)) * 8)
                               + (quad & 1) * 4] = pk;
        }

        // One barrier per tile: all waves past their Kt[cur] reads (so next
        // iter's stage may overwrite it) AND K(j+1) staged & visible (vmcnt
        // drain). PV below needs no barrier: Pb is wave-private, aV is in regs.
        __syncthreads();

        // ---- O^T += V^T * P^T
        #pragma unroll
        for (int kh = 0; kh < 2; ++kh) {
            short8 bP = *(const short8*)&Pb[wave][l16 * 64 + (((kh * 4 + quad) ^ (l16 & 7)) * 8)];
            #pragma unroll
            for (int dt = 0; dt < 4; ++dt)
                O[dt] = __builtin_amdgcn_mfma_f32_16x16x32_bf16(aV[kh][dt], bP, O[dt], 0, 0, 0);
        }

        cur ^= 1;
    }

    // ---- epilogue: cross-quad l reduction (once), then store
    float rs = l_run;
    rs += __shfl_xor(rs, 16);
    rs += __shfl_xor(rs, 32);
    float inv = 1.f / rs;
    const int t = t0 + wave * 16 + l16;
    #pragma unroll
    for (int dt = 0; dt < 4; ++dt) {
        #pragma unroll
        for (int r = 0; r < 4; ++r) {
            int dd = dt * 16 + quad * 4 + r;
            out[((size_t)b * D + hh * DH + dd) * T + t] = O[dt][r] * inv * sv[dd];
        }
    }
}

// -----------------------------------------------------------------------------
extern "C" void kernel_launch(void* const* d_in, const int* in_sizes, int n_in,
                              void* d_out, int out_size, void* d_ws, size_t ws_size,
                              hipStream_t stream) {
    const float* x      = (const float*)d_in[0];
    const float* qkv    = (const float*)d_in[1];
    const float* norm_w = (const float*)d_in[2];
    float* out = (float*)d_out;

    const size_t HB_BYTES = (size_t)2 * B * H * T * DH * 2;   // Q+K slabs
    const size_t VT_BYTES = (size_t)B * H * DH * T * 2;
    const size_t XT_BYTES = (size_t)B * T * D * 2;
    const size_t WT_BYTES = (size_t)3 * H * DH * D * 2;
    ushort* hb  = (ushort*)d_ws;
    ushort* vT  = (ushort*)((char*)d_ws + HB_BYTES);
    ushort* xT  = (ushort*)((char*)d_ws + HB_BYTES + VT_BYTES);
    ushort* WT  = (ushort*)((char*)d_ws + HB_BYTES + VT_BYTES + XT_BYTES);
    float*  ssq = (float*)((char*)d_ws + HB_BYTES + VT_BYTES + XT_BYTES + WT_BYTES);
    const int SSQ_N = 3 * B * H * DH;

    // x transpose also zeroes ssq (block 0) — it strictly precedes qkv_mm.
    transpose_lrelu<<<dim3(T / 64, D / 64, B), 256, 0, stream>>>(
        x, xT, T, D, (size_t)D * T, (size_t)T * D, 1, ssq, SSQ_N);
    transpose_lrelu<<<dim3(DH / 64, D / 64, 3 * H), 256, 0, stream>>>(
        qkv, WT, DH, D, (size_t)D * DH, (size_t)DH * D, 0, nullptr, 0);

    qkv_mm<<<dim3(T / 128, (3 * H * DH) / 128, B), 256, 0, stream>>>(xT, WT, hb, vT, ssq);
    flash_attn<<<dim3((T / 64) * B * H), 256, 0, stream>>>(hb, vT, ssq, norm_w, out);
}

// Round 6
// 155.462 us; speedup vs baseline: 1.4696x; 1.4696x over previous
//
#include <hip/hip_runtime.h>
#include <cstddef>

#define B   4
#define D   512
#define T   2048
#define H   8
#define DH  64
#define NEG_SLOPE 0.2f
#define EPS 1e-6f
#define LOG2E 1.44269504088896340736f

typedef __attribute__((ext_vector_type(8))) short short8;   // 8 x bf16 (4 VGPRs)
typedef __attribute__((ext_vector_type(4))) float float4v;  // 4 x f32
typedef __attribute__((ext_vector_type(2))) int   int2v;    // 2 x u32 (4 bf16)

__device__ __forceinline__ float bf2f(ushort u) {
    unsigned int x = ((unsigned int)u) << 16;
    return __builtin_bit_cast(float, x);
}
__device__ __forceinline__ ushort f2bf(float f) {
    unsigned int x = __builtin_bit_cast(unsigned int, f);
    x = x + 0x7fffu + ((x >> 16) & 1u);   // round-to-nearest-even
    return (ushort)(x >> 16);
}

// -----------------------------------------------------------------------------
// Kernel A: 64x64-tiled transpose fp32 -> bf16, optional leaky-ReLU.
// Block (0,0,0) also zeroes zbuf (ssq accumulator) when zbuf != nullptr.
// -----------------------------------------------------------------------------
__global__ __launch_bounds__(256) void transpose_lrelu(const float* __restrict__ src,
                                                       ushort* __restrict__ dst,
                                                       int src_ld, int dst_ld,
                                                       size_t src_mstride, size_t dst_mstride,
                                                       int do_lrelu,
                                                       float* __restrict__ zbuf, int zcount) {
    const int tid = threadIdx.x;
    if (zbuf != nullptr && blockIdx.x == 0 && blockIdx.y == 0 && blockIdx.z == 0) {
        for (int i = tid; i < zcount; i += 256) zbuf[i] = 0.f;
    }

    const int c0 = blockIdx.x * 64, r0 = blockIdx.y * 64;
    const float* s = src + blockIdx.z * src_mstride + (size_t)r0 * src_ld + c0;
    ushort*      d = dst + blockIdx.z * dst_mstride + (size_t)c0 * dst_ld + r0;

    __shared__ float Ls[64][68];

    const int rl = tid >> 4, c4 = (tid & 15) * 4;
    #pragma unroll
    for (int p = 0; p < 4; ++p) {
        float4 v = *(const float4*)(s + (size_t)(rl + p * 16) * src_ld + c4);
        if (do_lrelu) {
            v.x = fmaxf(v.x, NEG_SLOPE * v.x);
            v.y = fmaxf(v.y, NEG_SLOPE * v.y);
            v.z = fmaxf(v.z, NEG_SLOPE * v.z);
            v.w = fmaxf(v.w, NEG_SLOPE * v.w);
        }
        *(float4*)&Ls[rl + p * 16][c4] = v;
    }
    __syncthreads();

    const int tl = tid >> 2;
    #pragma unroll
    for (int it = 0; it < 2; ++it) {
        int ch = (tid & 3) + it * 4;
        ushort o[8];
        #pragma unroll
        for (int j = 0; j < 8; ++j) o[j] = f2bf(Ls[ch * 8 + j][tl]);
        *(uint4*)(d + (size_t)tl * dst_ld + ch * 8) = *(uint4*)o;
    }
}

// -----------------------------------------------------------------------------
// Kernel B: QKV GEMM via bf16 MFMA. C[b][t][gd] = sum_d xT[b][t][d] * WT[gd][d]
// Q/K heads -> hb[t][dh]; V heads -> vT[dd][t]. Accumulates per-channel sumsq.
// (round-0/3 version — carries the best measured total.)
// -----------------------------------------------------------------------------
__global__ __launch_bounds__(256) void qkv_mm(const ushort* __restrict__ xT,
                                              const ushort* __restrict__ WT,
                                              ushort* __restrict__ hb,
                                              ushort* __restrict__ vT,
                                              float* __restrict__ ssq) {
    const int tid = threadIdx.x, wave = tid >> 6, lane = tid & 63;
    const int quad = lane >> 4, l16 = lane & 15;
    const int wr = wave >> 1, wc = wave & 1;
    const int t0  = blockIdx.x * 128;
    const int gd0 = blockIdx.y * 128;
    const int b   = blockIdx.z;

    __shared__ ushort At[128 * 64];
    __shared__ ushort Bt[128 * 64];

    const ushort* xb = xT + (size_t)b * T * D + (size_t)t0 * D;
    const ushort* wb = WT + (size_t)gd0 * D;

    const int srow = lane >> 3;
    const int csrc = (lane & 7) ^ srow;

    float4v acc[4][4];
    #pragma unroll
    for (int i = 0; i < 4; ++i)
        #pragma unroll
        for (int j = 0; j < 4; ++j) acc[i][j] = (float4v){0.f, 0.f, 0.f, 0.f};

    for (int k0 = 0; k0 < D; k0 += 64) {
        #pragma unroll
        for (int i = 0; i < 4; ++i) {
            int rbase = wave * 32 + i * 8;
            int row = rbase + srow;
            const ushort* ga = xb + (size_t)row * D + k0 + csrc * 8;
            const ushort* gb = wb + (size_t)row * D + k0 + csrc * 8;
            __builtin_amdgcn_global_load_lds(
                (const __attribute__((address_space(1))) unsigned int*)ga,
                (__attribute__((address_space(3))) unsigned int*)&At[rbase * 64], 16, 0, 0);
            __builtin_amdgcn_global_load_lds(
                (const __attribute__((address_space(1))) unsigned int*)gb,
                (__attribute__((address_space(3))) unsigned int*)&Bt[rbase * 64], 16, 0, 0);
        }
        __syncthreads();

        #pragma unroll
        for (int kh = 0; kh < 2; ++kh) {
            short8 aF[4], bF[4];
            #pragma unroll
            for (int mt = 0; mt < 4; ++mt) {
                int row = wr * 64 + mt * 16 + l16;
                aF[mt] = *(const short8*)&At[row * 64 + (((kh * 4 + quad) ^ (l16 & 7)) * 8)];
            }
            #pragma unroll
            for (int nt = 0; nt < 4; ++nt) {
                int row = wc * 64 + nt * 16 + l16;
                bF[nt] = *(const short8*)&Bt[row * 64 + (((kh * 4 + quad) ^ (l16 & 7)) * 8)];
            }
            #pragma unroll
            for (int mt = 0; mt < 4; ++mt)
                #pragma unroll
                for (int nt = 0; nt < 4; ++nt)
                    acc[mt][nt] = __builtin_amdgcn_mfma_f32_16x16x32_bf16(
                        aF[mt], bF[nt], acc[mt][nt], 0, 0, 0);
        }
        __syncthreads();
    }

    const int g = blockIdx.y * 2 + wc;       // 0..23
    const int n = g >> 3, hh = g & 7;
    float colsq[4] = {0.f, 0.f, 0.f, 0.f};

    if (n < 2) {
        ushort* hbase = hb + (((size_t)n * B + b) * H + hh) * (size_t)T * DH;
        #pragma unroll
        for (int mt = 0; mt < 4; ++mt) {
            #pragma unroll
            for (int nt = 0; nt < 4; ++nt) {
                float4v c = acc[mt][nt];
                int dd = nt * 16 + l16;
                #pragma unroll
                for (int r = 0; r < 4; ++r) {
                    int t = t0 + wr * 64 + mt * 16 + quad * 4 + r;
                    hbase[(size_t)t * DH + dd] = f2bf(c[r]);
                    colsq[nt] += c[r] * c[r];
                }
            }
        }
    } else {
        ushort* vbase = vT + ((size_t)b * H + hh) * (size_t)DH * T;
        #pragma unroll
        for (int mt = 0; mt < 4; ++mt) {
            #pragma unroll
            for (int nt = 0; nt < 4; ++nt) {
                float4v c = acc[mt][nt];
                int dd = nt * 16 + l16;
                int t  = t0 + wr * 64 + mt * 16 + quad * 4;
                ushort4 pk;
                pk.x = f2bf(c[0]); pk.y = f2bf(c[1]);
                pk.z = f2bf(c[2]); pk.w = f2bf(c[3]);
                *(ushort4*)(vbase + (size_t)dd * T + t) = pk;
                colsq[nt] += c[0]*c[0] + c[1]*c[1] + c[2]*c[2] + c[3]*c[3];
            }
        }
    }
    #pragma unroll
    for (int nt = 0; nt < 4; ++nt) {
        float s = colsq[nt];
        s += __shfl_xor(s, 16);
        s += __shfl_xor(s, 32);
        if (quad == 0)
            atomicAdd(&ssq[(((size_t)n * B + b) * H + hh) * 64 + nt * 16 + l16], s);
    }
}

// -----------------------------------------------------------------------------
// Kernel C: flash attention, S^T = K*Q^T, NO online max. log2e folded into Q.
//
// Round-6: round-3 structure (16 q/wave, grid 1024, K dbuf + early-V staging,
// 2 barriers/tile) with the P LDS round-trip DELETED. Key identity: the QK^T
// C-frag per 16-key block mt (q=l16, key=quad*4+r) is exactly the B-operand
// layout of v_mfma_f32_16x16x16_bf16 (n=l16, k=quad*4+j). So P packs to 2
// VGPRs (same +0x8000/v_perm ops, register target) and PV runs 16 K=16 MFMAs
// (inline asm) with aV as 16 conflict-free ds_read_b64 (uniform 4 acc/bank).
// LDS/wave-tile 240 -> ~176 cyc; Pb's 8KB freed -> 24.6KB -> 6 blocks/CU.
// -----------------------------------------------------------------------------
__global__ __launch_bounds__(256, 4) void flash_attn(const ushort* __restrict__ hb,
                                                     const ushort* __restrict__ vT,
                                                     const float* __restrict__ ssq,
                                                     const float* __restrict__ norm_w,
                                                     float* __restrict__ out) {
    const int tid  = threadIdx.x;
    const int wave = tid >> 6;
    const int lane = tid & 63;
    const int quad = lane >> 4;
    const int l16  = lane & 15;

    // XCD-locality remap: all 32 t-tiles of a head land on one XCD
    const int lin  = blockIdx.x;
    const int head = ((lin & 7) << 2) | ((lin >> 3) & 3);   // b*H+hh
    const int t0   = (lin >> 5) * 64;
    const int b    = head >> 3, hh = head & 7;

    const size_t slab = (size_t)B * H * T * DH;
    const ushort* qp = hb + (size_t)head * T * DH;
    const ushort* kp = hb + slab + (size_t)head * T * DH;
    const ushort* vp = vT + (size_t)head * DH * T;

    __shared__ ushort Kt[2][64 * 64];     // 16 KB, double-buffered K tile
    __shared__ ushort Vt[64 * 64];        // 8 KB, single-buffered V tile
    __shared__ float fqk[64], sv[64];

    if (tid < 64) {
        float nw = norm_w[0];
        float mq = ssq[(0 * B * H + head) * 64 + tid] * (1.0f / T) + EPS;
        float mk = ssq[(1 * B * H + head) * 64 + tid] * (1.0f / T) + EPS;
        float mv = ssq[(2 * B * H + head) * 64 + tid] * (1.0f / T) + EPS;
        fqk[tid] = nw * nw * rsqrtf(mq) * rsqrtf(mk) * 0.125f * LOG2E;
        sv[tid]  = nw * rsqrtf(mv);
    }

    // ---- staging lane constants (pre-swizzled global source, linear LDS)
    const int srow = lane >> 3;
    const int csrc = (lane & 7) ^ srow;
    const ushort* kA = kp + (size_t)(wave * 16 + srow) * DH + csrc * 8;
    const ushort* kB = kp + (size_t)(wave * 16 + 8 + srow) * DH + csrc * 8;
    const ushort* vA = vp + (size_t)(wave * 16 + srow) * T + csrc * 8;
    const ushort* vB = vp + (size_t)(wave * 16 + 8 + srow) * T + csrc * 8;

    // ---- prologue: stage K tile 0 into buffer 0 (drained by the barrier below)
    __builtin_amdgcn_global_load_lds(
        (const __attribute__((address_space(1))) unsigned int*)kA,
        (__attribute__((address_space(3))) unsigned int*)&Kt[0][(wave * 16) * 64], 16, 0, 0);
    __builtin_amdgcn_global_load_lds(
        (const __attribute__((address_space(1))) unsigned int*)kB,
        (__attribute__((address_space(3))) unsigned int*)&Kt[0][(wave * 16 + 8) * 64], 16, 0, 0);

    // ---- Q B-frags (col = query = l16), pre-scaled by fqk (incl. log2e)
    __syncthreads();          // fqk/sv ready + K(0) staged & visible
    short8 bQ[2];
    {
        const ushort* qr = qp + (size_t)(t0 + wave * 16 + l16) * DH;
        #pragma unroll
        for (int kh = 0; kh < 2; ++kh) {
            short8 raw = *(const short8*)(qr + kh * 32 + quad * 8);
            #pragma unroll
            for (int j = 0; j < 8; ++j) {
                float f = bf2f((ushort)raw[j]) * fqk[kh * 32 + quad * 8 + j];
                bQ[kh][j] = (short)f2bf(f);
            }
        }
    }

    float l_run = 0.f;
    float4v O[4];
    #pragma unroll
    for (int dt = 0; dt < 4; ++dt) O[dt] = (float4v){0.f, 0.f, 0.f, 0.f};

    int cur = 0;
    for (int j0 = 0; j0 < T; j0 += 64) {
        // ---- issue V(j) stage now; consumed after the mid-tile barrier.
        __builtin_amdgcn_global_load_lds(
            (const __attribute__((address_space(1))) unsigned int*)(vA + j0),
            (__attribute__((address_space(3))) unsigned int*)&Vt[(wave * 16) * 64], 16, 0, 0);
        __builtin_amdgcn_global_load_lds(
            (const __attribute__((address_space(1))) unsigned int*)(vB + j0),
            (__attribute__((address_space(3))) unsigned int*)&Vt[(wave * 16 + 8) * 64], 16, 0, 0);

        // ---- issue K(j+1) prefetch into the other buffer
        if (j0 + 64 < T) {
            __builtin_amdgcn_global_load_lds(
                (const __attribute__((address_space(1))) unsigned int*)(kA + (size_t)(j0 + 64) * DH),
                (__attribute__((address_space(3))) unsigned int*)&Kt[cur ^ 1][(wave * 16) * 64], 16, 0, 0);
            __builtin_amdgcn_global_load_lds(
                (const __attribute__((address_space(1))) unsigned int*)(kB + (size_t)(j0 + 64) * DH),
                (__attribute__((address_space(3))) unsigned int*)&Kt[cur ^ 1][(wave * 16 + 8) * 64], 16, 0, 0);
        }

        // ---- S^T = K * Q^T from Kt[cur] (staged last iter, already visible)
        float4v S[4];
        #pragma unroll
        for (int mt = 0; mt < 4; ++mt) S[mt] = (float4v){0.f, 0.f, 0.f, 0.f};
        #pragma unroll
        for (int kh = 0; kh < 2; ++kh) {
            #pragma unroll
            for (int mt = 0; mt < 4; ++mt) {
                int row = mt * 16 + l16;
                short8 aK = *(const short8*)&Kt[cur][row * 64 + (((kh * 4 + quad) ^ (l16 & 7)) * 8)];
                S[mt] = __builtin_amdgcn_mfma_f32_16x16x32_bf16(aK, bQ[kh], S[mt], 0, 0, 0);
            }
        }

        // ---- P = exp2(S), partial l, pack to PV B-frags IN REGISTERS.
        // C-frag (q=l16, key=quad*4+r) == 16x16x16 B-frag (n=l16, k=quad*4+j):
        // no LDS round-trip needed.
        int2v pP[4];
        #pragma unroll
        for (int mt = 0; mt < 4; ++mt) {
            float p0 = __builtin_amdgcn_exp2f(S[mt][0]);
            float p1 = __builtin_amdgcn_exp2f(S[mt][1]);
            float p2 = __builtin_amdgcn_exp2f(S[mt][2]);
            float p3 = __builtin_amdgcn_exp2f(S[mt][3]);
            l_run += (p0 + p1) + (p2 + p3);
            unsigned int a0 = __builtin_bit_cast(unsigned int, p0) + 0x8000u;
            unsigned int a1 = __builtin_bit_cast(unsigned int, p1) + 0x8000u;
            unsigned int a2 = __builtin_bit_cast(unsigned int, p2) + 0x8000u;
            unsigned int a3 = __builtin_bit_cast(unsigned int, p3) + 0x8000u;
            pP[mt][0] = (int)__builtin_amdgcn_perm(a1, a0, 0x07060302u);   // [bf16(p0),bf16(p1)]
            pP[mt][1] = (int)__builtin_amdgcn_perm(a3, a2, 0x07060302u);   // [bf16(p2),bf16(p3)]
        }

        __syncthreads();      // V(j) + K(j+1) landed (issued ~a full phase ago)

        // ---- O^T += V^T * P^T : 16 x (16x16x16) MFMA, A from Vt (b64 reads)
        #pragma unroll
        for (int mt = 0; mt < 4; ++mt) {
            #pragma unroll
            for (int dt = 0; dt < 4; ++dt) {
                int row = dt * 16 + l16;
                // keys mt*16+quad*4..+3: 16B chunk (mt*2+(quad>>1))^(row&7),
                // 8B half (quad&1) — matches the staged XOR layout.
                int2v av = *(const int2v*)&Vt[row * 64
                               + (((mt * 2 + (quad >> 1)) ^ (row & 7)) * 8)
                               + (quad & 1) * 4];
                asm("v_mfma_f32_16x16x16_bf16 %0, %1, %2, %0"
                    : "+v"(O[dt]) : "v"(av), "v"(pP[mt]));
            }
        }

        __syncthreads();      // all waves done reading Vt before next V stage
        cur ^= 1;
    }

    // ---- epilogue: cross-quad l reduction (once), then store
    float rs = l_run;
    rs += __shfl_xor(rs, 16);
    rs += __shfl_xor(rs, 32);
    float inv = 1.f / rs;
    const int t = t0 + wave * 16 + l16;
    #pragma unroll
    for (int dt = 0; dt < 4; ++dt) {
        #pragma unroll
        for (int r = 0; r < 4; ++r) {
            int dd = dt * 16 + quad * 4 + r;
            out[((size_t)b * D + hh * DH + dd) * T + t] = O[dt][r] * inv * sv[dd];
        }
    }
}

// -----------------------------------------------------------------------------
extern "C" void kernel_launch(void* const* d_in, const int* in_sizes, int n_in,
                              void* d_out, int out_size, void* d_ws, size_t ws_size,
                              hipStream_t stream) {
    const float* x      = (const float*)d_in[0];
    const float* qkv    = (const float*)d_in[1];
    const float* norm_w = (const float*)d_in[2];
    float* out = (float*)d_out;

    const size_t HB_BYTES = (size_t)2 * B * H * T * DH * 2;   // Q+K slabs
    const size_t VT_BYTES = (size_t)B * H * DH * T * 2;
    const size_t XT_BYTES = (size_t)B * T * D * 2;
    const size_t WT_BYTES = (size_t)3 * H * DH * D * 2;
    ushort* hb  = (ushort*)d_ws;
    ushort* vT  = (ushort*)((char*)d_ws + HB_BYTES);
    ushort* xT  = (ushort*)((char*)d_ws + HB_BYTES + VT_BYTES);
    ushort* WT  = (ushort*)((char*)d_ws + HB_BYTES + VT_BYTES + XT_BYTES);
    float*  ssq = (float*)((char*)d_ws + HB_BYTES + VT_BYTES + XT_BYTES + WT_BYTES);
    const int SSQ_N = 3 * B * H * DH;

    // x transpose also zeroes ssq (block 0) — it strictly precedes qkv_mm.
    transpose_lrelu<<<dim3(T / 64, D / 64, B), 256, 0, stream>>>(
        x, xT, T, D, (size_t)D * T, (size_t)T * D, 1, ssq, SSQ_N);
    transpose_lrelu<<<dim3(DH / 64, D / 64, 3 * H), 256, 0, stream>>>(
        qkv, WT, DH, D, (size_t)D * DH, (size_t)DH * D, 0, nullptr, 0);

    qkv_mm<<<dim3(T / 128, (3 * H * DH) / 128, B), 256, 0, stream>>>(xT, WT, hb, vT, ssq);
    flash_attn<<<dim3((T / 64) * B * H), 256, 0, stream>>>(hb, vT, ssq, norm_w, out);
}

// Round 8
// 154.371 us; speedup vs baseline: 1.4800x; 1.0071x over previous
//
#include <hip/hip_runtime.h>
#include <cstddef>

#define B   4
#define D   512
#define T   2048
#define H   8
#define DH  64
#define NEG_SLOPE 0.2f
#define EPS 1e-6f
#define LOG2E 1.44269504088896340736f

typedef __attribute__((ext_vector_type(8))) short short8;   // 8 x bf16 (4 VGPRs)
typedef __attribute__((ext_vector_type(4))) float float4v;  // 4 x f32
typedef __attribute__((ext_vector_type(2))) int   int2v;    // 2 x u32 (4 bf16)

__device__ __forceinline__ float bf2f(ushort u) {
    unsigned int x = ((unsigned int)u) << 16;
    return __builtin_bit_cast(float, x);
}
__device__ __forceinline__ ushort f2bf(float f) {
    unsigned int x = __builtin_bit_cast(unsigned int, f);
    x = x + 0x7fffu + ((x >> 16) & 1u);   // round-to-nearest-even
    return (ushort)(x >> 16);
}

#define GLD16(gptr, lptr) __builtin_amdgcn_global_load_lds( \
    (const __attribute__((address_space(1))) unsigned int*)(gptr), \
    (__attribute__((address_space(3))) unsigned int*)(lptr), 16, 0, 0)

// -----------------------------------------------------------------------------
// Kernel A: BOTH transposes in one launch (1D grid, 1216 blocks).
// bid < 1024: x (B,D,T) fp32 -> xT (B,T,D) bf16 with leaky-ReLU (+ssq zero @0).
// bid >= 1024: qkv (3H,D,DH) fp32 -> WT (3H,DH,D) bf16.
// Body identical to the proven transpose_lrelu; only block decode differs.
// -----------------------------------------------------------------------------
__global__ __launch_bounds__(256) void transpose_both(const float* __restrict__ x,
                                                      ushort* __restrict__ xT,
                                                      const float* __restrict__ qkv,
                                                      ushort* __restrict__ WT,
                                                      float* __restrict__ ssq, int zcount) {
    const int tid = threadIdx.x;
    const int bid = blockIdx.x;

    const float* src; ushort* dst;
    int src_ld, dst_ld, do_lrelu, bx, by, bz;
    size_t src_ms, dst_ms;
    if (bid < 1024) {
        bx = bid & 31; by = (bid >> 5) & 7; bz = bid >> 8;       // (32,8,4)
        src = x; dst = xT; src_ld = T; dst_ld = D;
        src_ms = (size_t)D * T; dst_ms = (size_t)T * D; do_lrelu = 1;
        if (bid == 0) for (int i = tid; i < zcount; i += 256) ssq[i] = 0.f;
    } else {
        int wb = bid - 1024;                                      // (1,8,24)
        bx = 0; by = wb & 7; bz = wb >> 3;
        src = qkv; dst = WT; src_ld = DH; dst_ld = D;
        src_ms = (size_t)D * DH; dst_ms = (size_t)DH * D; do_lrelu = 0;
    }

    const int c0 = bx * 64, r0 = by * 64;
    const float* s = src + bz * src_ms + (size_t)r0 * src_ld + c0;
    ushort*      d = dst + bz * dst_ms + (size_t)c0 * dst_ld + r0;

    __shared__ float Ls[64][68];

    const int rl = tid >> 4, c4 = (tid & 15) * 4;
    #pragma unroll
    for (int p = 0; p < 4; ++p) {
        float4 v = *(const float4*)(s + (size_t)(rl + p * 16) * src_ld + c4);
        if (do_lrelu) {
            v.x = fmaxf(v.x, NEG_SLOPE * v.x);
            v.y = fmaxf(v.y, NEG_SLOPE * v.y);
            v.z = fmaxf(v.z, NEG_SLOPE * v.z);
            v.w = fmaxf(v.w, NEG_SLOPE * v.w);
        }
        *(float4*)&Ls[rl + p * 16][c4] = v;
    }
    __syncthreads();

    const int tl = tid >> 2;
    #pragma unroll
    for (int it = 0; it < 2; ++it) {
        int ch = (tid & 3) + it * 4;
        ushort o[8];
        #pragma unroll
        for (int j = 0; j < 8; ++j) o[j] = f2bf(Ls[ch * 8 + j][tl]);
        *(uint4*)(d + (size_t)tl * dst_ld + ch * 8) = *(uint4*)o;
    }
}

// -----------------------------------------------------------------------------
// Kernel B: QKV GEMM via bf16 MFMA. C[b][t][gd] = sum_d xT[b][t][d] * WT[gd][d]
// Q/K heads -> hb[t][dh]; V heads -> vT[dd][t]. Accumulates per-channel sumsq.
//
// Round-8: t-tile 128 -> 64. Grid 768 -> 1536 blocks, LDS 32 -> 24 KB,
// acc[4][4] -> [2][4], __launch_bounds__(256,5) -> ~5 blocks/CU = 20 waves/CU
// (was 3 blocks = 12 waves). Theory: qkv_mm (like flash) is latency-bound, so
// TLP is the lever; round-4 showed its K-loop schedule is NOT the cost.
// Staging/swizzle/read/epilogue patterns identical to the proven version;
// swizzle identity row&7 == l16&7 still holds (all row offsets are mult of 8).
// -----------------------------------------------------------------------------
__global__ __launch_bounds__(256, 5) void qkv_mm(const ushort* __restrict__ xT,
                                                 const ushort* __restrict__ WT,
                                                 ushort* __restrict__ hb,
                                                 ushort* __restrict__ vT,
                                                 float* __restrict__ ssq) {
    const int tid = threadIdx.x, wave = tid >> 6, lane = tid & 63;
    const int quad = lane >> 4, l16 = lane & 15;
    const int wr = wave >> 1, wc = wave & 1;
    const int t0  = blockIdx.x * 64;
    const int gd0 = blockIdx.y * 128;
    const int b   = blockIdx.z;

    __shared__ ushort At[64 * 64];        // 8 KB  (t rows)
    __shared__ ushort Bt[128 * 64];       // 16 KB (gd rows)

    const ushort* xb = xT + (size_t)b * T * D + (size_t)t0 * D;
    const ushort* wb = WT + (size_t)gd0 * D;

    const int srow = lane >> 3;
    const int csrc = (lane & 7) ^ srow;

    float4v acc[2][4];
    #pragma unroll
    for (int i = 0; i < 2; ++i)
        #pragma unroll
        for (int j = 0; j < 4; ++j) acc[i][j] = (float4v){0.f, 0.f, 0.f, 0.f};

    for (int k0 = 0; k0 < D; k0 += 64) {
        #pragma unroll
        for (int i = 0; i < 2; ++i) {                 // A: 64 rows, 2 GLD16/wave
            int rbase = wave * 16 + i * 8;
            GLD16(xb + (size_t)(rbase + srow) * D + k0 + csrc * 8, &At[rbase * 64]);
        }
        #pragma unroll
        for (int i = 0; i < 4; ++i) {                 // B: 128 rows, 4 GLD16/wave
            int rbase = wave * 32 + i * 8;
            GLD16(wb + (size_t)(rbase + srow) * D + k0 + csrc * 8, &Bt[rbase * 64]);
        }
        __syncthreads();

        #pragma unroll
        for (int kh = 0; kh < 2; ++kh) {
            short8 aF[2], bF[4];
            #pragma unroll
            for (int mt = 0; mt < 2; ++mt) {
                int row = wr * 32 + mt * 16 + l16;
                aF[mt] = *(const short8*)&At[row * 64 + (((kh * 4 + quad) ^ (l16 & 7)) * 8)];
            }
            #pragma unroll
            for (int nt = 0; nt < 4; ++nt) {
                int row = wc * 64 + nt * 16 + l16;
                bF[nt] = *(const short8*)&Bt[row * 64 + (((kh * 4 + quad) ^ (l16 & 7)) * 8)];
            }
            #pragma unroll
            for (int mt = 0; mt < 2; ++mt)
                #pragma unroll
                for (int nt = 0; nt < 4; ++nt)
                    acc[mt][nt] = __builtin_amdgcn_mfma_f32_16x16x32_bf16(
                        aF[mt], bF[nt], acc[mt][nt], 0, 0, 0);
        }
        __syncthreads();
    }

    const int g = blockIdx.y * 2 + wc;       // 0..23
    const int n = g >> 3, hh = g & 7;
    float colsq[4] = {0.f, 0.f, 0.f, 0.f};

    if (n < 2) {
        ushort* hbase = hb + (((size_t)n * B + b) * H + hh) * (size_t)T * DH;
        #pragma unroll
        for (int mt = 0; mt < 2; ++mt) {
            #pragma unroll
            for (int nt = 0; nt < 4; ++nt) {
                float4v c = acc[mt][nt];
                int dd = nt * 16 + l16;
                #pragma unroll
                for (int r = 0; r < 4; ++r) {
                    int t = t0 + wr * 32 + mt * 16 + quad * 4 + r;
                    hbase[(size_t)t * DH + dd] = f2bf(c[r]);
                    colsq[nt] += c[r] * c[r];
                }
            }
        }
    } else {
        ushort* vbase = vT + ((size_t)b * H + hh) * (size_t)DH * T;
        #pragma unroll
        for (int mt = 0; mt < 2; ++mt) {
            #pragma unroll
            for (int nt = 0; nt < 4; ++nt) {
                float4v c = acc[mt][nt];
                int dd = nt * 16 + l16;
                int t  = t0 + wr * 32 + mt * 16 + quad * 4;
                ushort4 pk;
                pk.x = f2bf(c[0]); pk.y = f2bf(c[1]);
                pk.z = f2bf(c[2]); pk.w = f2bf(c[3]);
                *(ushort4*)(vbase + (size_t)dd * T + t) = pk;
                colsq[nt] += c[0]*c[0] + c[1]*c[1] + c[2]*c[2] + c[3]*c[3];
            }
        }
    }
    #pragma unroll
    for (int nt = 0; nt < 4; ++nt) {
        float s = colsq[nt];
        s += __shfl_xor(s, 16);
        s += __shfl_xor(s, 32);
        if (quad == 0)
            atomicAdd(&ssq[(((size_t)n * B + b) * H + hh) * 64 + nt * 16 + l16], s);
    }
}

// -----------------------------------------------------------------------------
// Kernel C: flash attention — round-6 version VERBATIM (verified, 61 us).
// S^T = K*Q^T, no online max, register-P (QK C-frag == 16x16x16 B-frag),
// K dbuf + early-V staging, 2 barriers/tile.
// -----------------------------------------------------------------------------
__global__ __launch_bounds__(256, 4) void flash_attn(const ushort* __restrict__ hb,
                                                     const ushort* __restrict__ vT,
                                                     const float* __restrict__ ssq,
                                                     const float* __restrict__ norm_w,
                                                     float* __restrict__ out) {
    const int tid  = threadIdx.x;
    const int wave = tid >> 6;
    const int lane = tid & 63;
    const int quad = lane >> 4;
    const int l16  = lane & 15;

    // XCD-locality remap: all 32 t-tiles of a head land on one XCD
    const int lin  = blockIdx.x;
    const int head = ((lin & 7) << 2) | ((lin >> 3) & 3);   // b*H+hh
    const int t0   = (lin >> 5) * 64;
    const int b    = head >> 3, hh = head & 7;

    const size_t slab = (size_t)B * H * T * DH;
    const ushort* qp = hb + (size_t)head * T * DH;
    const ushort* kp = hb + slab + (size_t)head * T * DH;
    const ushort* vp = vT + (size_t)head * DH * T;

    __shared__ ushort Kt[2][64 * 64];     // 16 KB, double-buffered K tile
    __shared__ ushort Vt[64 * 64];        // 8 KB, single-buffered V tile
    __shared__ float fqk[64], sv[64];

    if (tid < 64) {
        float nw = norm_w[0];
        float mq = ssq[(0 * B * H + head) * 64 + tid] * (1.0f / T) + EPS;
        float mk = ssq[(1 * B * H + head) * 64 + tid] * (1.0f / T) + EPS;
        float mv = ssq[(2 * B * H + head) * 64 + tid] * (1.0f / T) + EPS;
        fqk[tid] = nw * nw * rsqrtf(mq) * rsqrtf(mk) * 0.125f * LOG2E;
        sv[tid]  = nw * rsqrtf(mv);
    }

    // ---- staging lane constants (pre-swizzled global source, linear LDS)
    const int srow = lane >> 3;
    const int csrc = (lane & 7) ^ srow;
    const ushort* kA = kp + (size_t)(wave * 16 + srow) * DH + csrc * 8;
    const ushort* kB = kp + (size_t)(wave * 16 + 8 + srow) * DH + csrc * 8;
    const ushort* vA = vp + (size_t)(wave * 16 + srow) * T + csrc * 8;
    const ushort* vB = vp + (size_t)(wave * 16 + 8 + srow) * T + csrc * 8;

    // ---- prologue: stage K tile 0 into buffer 0 (drained by the barrier below)
    GLD16(kA, &Kt[0][(wave * 16) * 64]);
    GLD16(kB, &Kt[0][(wave * 16 + 8) * 64]);

    // ---- Q B-frags (col = query = l16), pre-scaled by fqk (incl. log2e)
    __syncthreads();          // fqk/sv ready + K(0) staged & visible
    short8 bQ[2];
    {
        const ushort* qr = qp + (size_t)(t0 + wave * 16 + l16) * DH;
        #pragma unroll
        for (int kh = 0; kh < 2; ++kh) {
            short8 raw = *(const short8*)(qr + kh * 32 + quad * 8);
            #pragma unroll
            for (int j = 0; j < 8; ++j) {
                float f = bf2f((ushort)raw[j]) * fqk[kh * 32 + quad * 8 + j];
                bQ[kh][j] = (short)f2bf(f);
            }
        }
    }

    float l_run = 0.f;
    float4v O[4];
    #pragma unroll
    for (int dt = 0; dt < 4; ++dt) O[dt] = (float4v){0.f, 0.f, 0.f, 0.f};

    int cur = 0;
    for (int j0 = 0; j0 < T; j0 += 64) {
        // ---- issue V(j) stage now; consumed after the mid-tile barrier.
        GLD16(vA + j0, &Vt[(wave * 16) * 64]);
        GLD16(vB + j0, &Vt[(wave * 16 + 8) * 64]);

        // ---- issue K(j+1) prefetch into the other buffer
        if (j0 + 64 < T) {
            GLD16(kA + (size_t)(j0 + 64) * DH, &Kt[cur ^ 1][(wave * 16) * 64]);
            GLD16(kB + (size_t)(j0 + 64) * DH, &Kt[cur ^ 1][(wave * 16 + 8) * 64]);
        }

        // ---- S^T = K * Q^T from Kt[cur] (staged last iter, already visible)
        float4v S[4];
        #pragma unroll
        for (int mt = 0; mt < 4; ++mt) S[mt] = (float4v){0.f, 0.f, 0.f, 0.f};
        #pragma unroll
        for (int kh = 0; kh < 2; ++kh) {
            #pragma unroll
            for (int mt = 0; mt < 4; ++mt) {
                int row = mt * 16 + l16;
                short8 aK = *(const short8*)&Kt[cur][row * 64 + (((kh * 4 + quad) ^ (l16 & 7)) * 8)];
                S[mt] = __builtin_amdgcn_mfma_f32_16x16x32_bf16(aK, bQ[kh], S[mt], 0, 0, 0);
            }
        }

        // ---- P = exp2(S), partial l, pack to PV B-frags IN REGISTERS.
        int2v pP[4];
        #pragma unroll
        for (int mt = 0; mt < 4; ++mt) {
            float p0 = __builtin_amdgcn_exp2f(S[mt][0]);
            float p1 = __builtin_amdgcn_exp2f(S[mt][1]);
            float p2 = __builtin_amdgcn_exp2f(S[mt][2]);
            float p3 = __builtin_amdgcn_exp2f(S[mt][3]);
            l_run += (p0 + p1) + (p2 + p3);
            unsigned int a0 = __builtin_bit_cast(unsigned int, p0) + 0x8000u;
            unsigned int a1 = __builtin_bit_cast(unsigned int, p1) + 0x8000u;
            unsigned int a2 = __builtin_bit_cast(unsigned int, p2) + 0x8000u;
            unsigned int a3 = __builtin_bit_cast(unsigned int, p3) + 0x8000u;
            pP[mt][0] = (int)__builtin_amdgcn_perm(a1, a0, 0x07060302u);   // [bf16(p0),bf16(p1)]
            pP[mt][1] = (int)__builtin_amdgcn_perm(a3, a2, 0x07060302u);   // [bf16(p2),bf16(p3)]
        }

        __syncthreads();      // V(j) + K(j+1) landed (issued ~a full phase ago)

        // ---- O^T += V^T * P^T : 16 x (16x16x16) MFMA, A from Vt (b64 reads)
        #pragma unroll
        for (int mt = 0; mt < 4; ++mt) {
            #pragma unroll
            for (int dt = 0; dt < 4; ++dt) {
                int row = dt * 16 + l16;
                int2v av = *(const int2v*)&Vt[row * 64
                               + (((mt * 2 + (quad >> 1)) ^ (row & 7)) * 8)
                               + (quad & 1) * 4];
                asm("v_mfma_f32_16x16x16_bf16 %0, %1, %2, %0"
                    : "+v"(O[dt]) : "v"(av), "v"(pP[mt]));
            }
        }

        __syncthreads();      // all waves done reading Vt before next V stage
        cur ^= 1;
    }

    // ---- epilogue: cross-quad l reduction (once), then store
    float rs = l_run;
    rs += __shfl_xor(rs, 16);
    rs += __shfl_xor(rs, 32);
    float inv = 1.f / rs;
    const int t = t0 + wave * 16 + l16;
    #pragma unroll
    for (int dt = 0; dt < 4; ++dt) {
        #pragma unroll
        for (int r = 0; r < 4; ++r) {
            int dd = dt * 16 + quad * 4 + r;
            out[((size_t)b * D + hh * DH + dd) * T + t] = O[dt][r] * inv * sv[dd];
        }
    }
}

// -----------------------------------------------------------------------------
extern "C" void kernel_launch(void* const* d_in, const int* in_sizes, int n_in,
                              void* d_out, int out_size, void* d_ws, size_t ws_size,
                              hipStream_t stream) {
    const float* x      = (const float*)d_in[0];
    const float* qkv    = (const float*)d_in[1];
    const float* norm_w = (const float*)d_in[2];
    float* out = (float*)d_out;

    const size_t HB_BYTES = (size_t)2 * B * H * T * DH * 2;   // Q+K slabs
    const size_t VT_BYTES = (size_t)B * H * DH * T * 2;
    const size_t XT_BYTES = (size_t)B * T * D * 2;
    const size_t WT_BYTES = (size_t)3 * H * DH * D * 2;
    ushort* hb  = (ushort*)d_ws;
    ushort* vT  = (ushort*)((char*)d_ws + HB_BYTES);
    ushort* xT  = (ushort*)((char*)d_ws + HB_BYTES + VT_BYTES);
    ushort* WT  = (ushort*)((char*)d_ws + HB_BYTES + VT_BYTES + XT_BYTES);
    float*  ssq = (float*)((char*)d_ws + HB_BYTES + VT_BYTES + XT_BYTES + WT_BYTES);
    const int SSQ_N = 3 * B * H * DH;

    // merged transposes (x + weights); block 0 zeroes ssq before qkv_mm.
    transpose_both<<<dim3(1024 + 192), 256, 0, stream>>>(x, xT, qkv, WT, ssq, SSQ_N);

    qkv_mm<<<dim3(T / 64, (3 * H * DH) / 128, B), 256, 0, stream>>>(xT, WT, hb, vT, ssq);
    flash_attn<<<dim3((T / 64) * B * H), 256, 0, stream>>>(hb, vT, ssq, norm_w, out);
}